// Round 17
// baseline (655.382 us; speedup 1.0000x reference)
//
#include <hip/hip_runtime.h>

#define PER  149796
#define HDIM 64
#define EDIM 32
#define NIOU 192
#define STG  96               // staged child rows per chunk
#define NS   256              // root accumulator slices

typedef _Float16 f16;
typedef _Float16 f16x8 __attribute__((ext_vector_type(8)));
typedef _Float16 f16x2 __attribute__((ext_vector_type(2)));
typedef float    f32x4 __attribute__((ext_vector_type(4)));

typedef __attribute__((address_space(1))) const unsigned gu32;
typedef __attribute__((address_space(3))) unsigned lu32;

__device__ __forceinline__ float sigf(float x){ return 1.0f/(1.0f+__expf(-x)); }
__device__ __forceinline__ float tanh_f(float x){
  float ax = fabsf(x);
  float e  = __expf(-2.0f*ax);
  float t  = (1.0f - e)/(1.0f + e);
  return x < 0.0f ? -t : t;
}

// ================= cascaded sort build =================
// Level-1 sorted order = identity; level d+1 sorted by parent's sorted position.
// Both read AND write sides of every level kernel become contiguous.

__global__ __launch_bounds__(256) void init1_kernel(
    const int* __restrict__ tok, int* __restrict__ spos,
    int* __restrict__ stok1, int* __restrict__ ptok1, int* __restrict__ soff_all)
{
  int i = blockIdx.x*256 + threadIdx.x;
  if (i < PER){
    spos[i]  = i;
    stok1[i] = tok[1+i];
    ptok1[i] = tok[0];
  }
  if (i < 6) soff_all[(size_t)i*(PER+1) + PER] = PER;   // every level has PER children
}

__global__ __launch_bounds__(256) void countL_kernel(
    const int* __restrict__ parent, const int* __restrict__ spos_cur,
    int* __restrict__ cnt, int coff, int poff)
{
  int i = blockIdx.x*256 + threadIdx.x;
  if (i >= PER) return;
  int s = spos_cur[parent[coff+i] - poff];
  atomicAdd(&cnt[s], 1);
}

// scan over PER counts: 147 blocks x 1024 elems
__global__ __launch_bounds__(256) void scan1_kernel(const int* __restrict__ cnt, int* __restrict__ bsum){
  __shared__ int sc[256];
  int b=blockIdx.x, t=threadIdx.x;
  int base=b*1024+t*4;
  int s=0;
  #pragma unroll
  for (int e=0;e<4;e++){ int idx=base+e; if (idx<PER) s+=cnt[idx]; }
  sc[t]=s; __syncthreads();
  for (int d=128; d>0; d>>=1){ if (t<d) sc[t]+=sc[t+d]; __syncthreads(); }
  if (t==0) bsum[b]=sc[0];
}

// block-base scan (done redundantly per block) + intra-block scan -> soff, cursor
__global__ __launch_bounds__(256) void scan23_kernel(
    const int* __restrict__ cnt, const int* __restrict__ bsum,
    int* __restrict__ soff, int* __restrict__ cursor)
{
  __shared__ int bb[256];
  __shared__ int sc[256];
  int b=blockIdx.x, t=threadIdx.x;
  const int nb = (PER + 1023)/1024;   // 147
  bb[t] = (t<nb)? bsum[t] : 0;
  __syncthreads();
  for (int d=1; d<256; d<<=1){
    int v=(t>=d)?bb[t-d]:0; __syncthreads();
    bb[t]+=v; __syncthreads();
  }
  int bbase = (b==0)?0:bb[b-1];
  int base=b*1024+t*4;
  int e0=(base  <PER)?cnt[base  ]:0;
  int e1=(base+1<PER)?cnt[base+1]:0;
  int e2=(base+2<PER)?cnt[base+2]:0;
  int e3=(base+3<PER)?cnt[base+3]:0;
  sc[t]=e0+e1+e2+e3; __syncthreads();
  for (int d=1; d<256; d<<=1){
    int v=(t>=d)?sc[t-d]:0; __syncthreads();
    sc[t]+=v; __syncthreads();
  }
  int x = bbase + ((t==0)?0:sc[t-1]);
  if (base  <PER){ soff[base  ]=x;          cursor[base  ]=x; }
  if (base+1<PER){ soff[base+1]=x+e0;       cursor[base+1]=x+e0; }
  if (base+2<PER){ soff[base+2]=x+e0+e1;    cursor[base+2]=x+e0+e1; }
  if (base+3<PER){ soff[base+3]=x+e0+e1+e2; cursor[base+3]=x+e0+e1+e2; }
}

// scatter: assign sorted positions to children; gather their tokens into sorted order.
// Also zeroes cnt for the next level's count (cnt is dead after scan23).
__global__ __launch_bounds__(256) void scatterL_kernel(
    const int* __restrict__ parent, const int* __restrict__ tok,
    const int* __restrict__ spos_cur, int* __restrict__ cursor,
    int* __restrict__ spos_next, int* __restrict__ stok_next, int* __restrict__ ptok_next,
    int* __restrict__ cnt, int coff, int poff)
{
  int i = blockIdx.x*256 + threadIdx.x;
  if (i >= PER) return;
  cnt[i] = 0;
  int g  = coff + i;
  int pg = parent[g];
  int s  = spos_cur[pg - poff];
  int pos = atomicAdd(&cursor[s], 1);
  spos_next[i]   = pos;
  stok_next[pos] = tok[g];
  ptok_next[pos] = tok[pg];
}

// ================= tables + MFMA packs (fused) =================
// B-frag order for mfma_f32_16x16x32_f16 (verified R4): lane L: n=t*16+(L&15), k=s*32+(L>>4)*8+j
__global__ __launch_bounds__(256) void tablepack_kernel(
    const float* __restrict__ emb, const float* __restrict__ Wiou, const float* __restrict__ biou,
    const float* __restrict__ Wf, const float* __restrict__ bf,
    const float* __restrict__ Uf, const float* __restrict__ Uiou,
    float* __restrict__ embWiou, float* __restrict__ embWf,
    f16* __restrict__ Bfp, f16* __restrict__ Biop)
{
  if (blockIdx.x < 1024){
    int v = blockIdx.x;
    int m = threadIdx.x;
    const float* x = emb + (size_t)v*EDIM;
    if (m < NIOU){
      float a = biou[m];
      #pragma unroll
      for (int e=0;e<EDIM;e++) a += Wiou[m*EDIM+e]*x[e];
      embWiou[(size_t)v*NIOU + m] = a;
    } else {
      int mm = m - NIOU;
      float a = bf[mm];
      #pragma unroll
      for (int e=0;e<EDIM;e++) a += Wf[mm*EDIM+e]*x[e];
      embWf[(size_t)v*HDIM + mm] = a;
    }
  } else {
    for (int i = threadIdx.x; i < 2*4*64*8; i += 256){
      int j = i & 7, L = (i>>3)&63, st = i>>9;
      int t = st & 3, s = st >> 2;
      int k = s*32 + (L>>4)*8 + j;
      int n = t*16 + (L&15);
      Bfp[i] = (f16)Uf[n*HDIM + k];
    }
    for (int i = threadIdx.x; i < 2*12*64*8; i += 256){
      int j = i & 7, L = (i>>3)&63, st = i>>9;
      int t = st % 12, s = st / 12;
      int k = s*32 + (L>>4)*8 + j;
      int n = t*16 + (L&15);
      Biop[i] = (f16)Uiou[n*HDIM + k];
    }
  }
}

// ================= level kernel (fully streaming both sides) =================
// 4 waves x 16 parents = 64 sorted-consecutive parents per block.
// mode: 0 = leaf (no gather, no iou MFMA), 1 = mid, 2 = level-1 (fused root reduce)
// phase1: chunked global_load_lds staging of the block's CONTIGUOUS child range,
//         segmented sum from LDS. phase2: iou MFMA + cell epilogue.
// phase3: Uf MFMA on own h, write {h,fc} at own sorted row (contiguous).
__global__ __launch_bounds__(256) void level_kernel(
    const int* __restrict__ stokL, const int* __restrict__ ptokL,
    const int* __restrict__ soffL,
    const float* __restrict__ embWiou, const float* __restrict__ embWf,
    const f16* __restrict__ Biopack, const f16* __restrict__ Ufpack,
    const f16x2* __restrict__ HFin, f16x2* __restrict__ HFout,
    float* __restrict__ rootslice, int mode)
{
  __shared__ __align__(16) char smem[STG*HDIM*4];   // 24576 B
  f16x2* stage = (f16x2*)smem;
  f16*   Ah    = (f16*)smem;                        // 64*72*2 = 9216 (aliased)
  f16*   FAf   = (f16*)(smem + 9216);               // 64*68*2 = 8704
  int lane = threadIdx.x & 63;
  int wv   = __builtin_amdgcn_readfirstlane(threadIdx.x >> 6);
  int p0   = wv*16;
  int j0b  = blockIdx.x*64;
  int j0   = j0b + p0;
  int q = lane>>4, c16 = lane&15;

  float hs[16], fa[16];
  #pragma unroll
  for (int i=0;i<16;i++){ hs[i]=0.f; fa[i]=0.f; }

  if (mode != 0){
    int ei = j0b + 64; if (ei > PER) ei = PER;
    int S = soffL[j0b];
    int E = soffL[ei];
    int sB[17];
    #pragma unroll
    for (int i=0;i<=16;i++){
      int jj = j0 + i; if (jj > PER) jj = PER;
      sB[i] = soffL[jj];
    }
    const unsigned* HFinU = (const unsigned*)HFin;
    for (int cb = S; cb < E; cb += STG){
      int n = E - cb; if (n > STG) n = STG;
      for (int r = wv; r < n; r += 4){
        gu32* gp = (gu32*)(HFinU + (size_t)(cb+r)*HDIM) + lane;   // contiguous rows
        __builtin_amdgcn_global_load_lds(gp, (lu32*)&stage[r*HDIM], 4, 0, 0);
      }
      __syncthreads();
      int lim = cb + n;
      #pragma unroll
      for (int i=0;i<16;i++){
        int lo = sB[i]   > cb  ? sB[i]   : cb;
        int hi = sB[i+1] < lim ? sB[i+1] : lim;
        for (int p=lo; p<hi; ++p){
          f16x2 v = stage[(p-cb)*HDIM + lane];
          hs[i] += (float)v.x; fa[i] += (float)v.y;
        }
      }
      __syncthreads();
    }
  }
  // stage consumed (or never used) — safe to write aliased Ah/FAf
  #pragma unroll
  for (int i=0;i<16;i++){
    Ah[(p0+i)*72 + lane]  = (f16)hs[i];
    FAf[(p0+i)*68 + lane] = (f16)fa[i];
  }
  __syncthreads();
  // ---- phase 2: iou MFMA + epilogue
  const f16x8* Bp = (const f16x8*)Biopack;
  f32x4 acc[12];
  #pragma unroll
  for (int nt=0;nt<12;nt++) acc[nt] = (f32x4){0.f,0.f,0.f,0.f};
  if (mode != 0){
    f16x8 A0 = *(const f16x8*)(Ah + (p0+c16)*72 + q*8);
    f16x8 A1 = *(const f16x8*)(Ah + (p0+c16)*72 + 32 + q*8);
    #pragma unroll
    for (int nt=0;nt<12;nt++){
      f16x8 B0 = Bp[nt*64 + lane];
      f16x8 B1 = Bp[(12+nt)*64 + lane];
      acc[nt] = __builtin_amdgcn_mfma_f32_16x16x32_f16(A0, B0, acc[nt], 0,0,0);
      acc[nt] = __builtin_amdgcn_mfma_f32_16x16x32_f16(A1, B1, acc[nt], 0,0,0);
    }
  }
  float cc[4][4];
  f16   hh[4][4];
  int   wt_[4]; bool ok_[4];
  #pragma unroll
  for (int r=0;r<4;r++){
    int j = j0 + q*4 + r;
    bool ok = j < PER;
    int jl = ok ? j : PER-1;
    int tk = stokL[jl];
    const float* tr = embWiou + (size_t)tk*NIOU;
    wt_[r] = ptokL[jl];
    ok_[r] = ok;
    int lrow = p0 + q*4 + r;
    #pragma unroll
    for (int nt=0;nt<4;nt++){
      int col = nt*16 + c16;
      float ai = acc[nt][r]   + tr[col];
      float ao = acc[nt+4][r] + tr[64+col];
      float au = acc[nt+8][r] + tr[128+col];
      float fav = (float)FAf[lrow*68 + col];
      float c = sigf(ai)*tanh_f(au) + fav;
      float h = sigf(ao)*tanh_f(c);
      cc[r][nt] = c;
      hh[r][nt] = (f16)h;
    }
  }
  __syncthreads();
  // ---- phase 3: h -> Ah (A-layout), Uf MFMA, write/reduce
  #pragma unroll
  for (int r=0;r<4;r++)
    #pragma unroll
    for (int nt=0;nt<4;nt++)
      Ah[(p0+q*4+r)*72 + nt*16 + c16] = hh[r][nt];
  __syncthreads();
  f16x8 H0 = *(const f16x8*)(Ah + (p0+c16)*72 + q*8);
  f16x8 H1 = *(const f16x8*)(Ah + (p0+c16)*72 + 32 + q*8);
  const f16x8* Up = (const f16x8*)Ufpack;
  f32x4 g4[4];
  #pragma unroll
  for (int nt=0;nt<4;nt++) g4[nt] = (f32x4){0.f,0.f,0.f,0.f};
  #pragma unroll
  for (int nt=0;nt<4;nt++){
    f16x8 B0 = Up[nt*64 + lane];
    f16x8 B1 = Up[(4+nt)*64 + lane];
    g4[nt] = __builtin_amdgcn_mfma_f32_16x16x32_f16(H0, B0, g4[nt], 0,0,0);
    g4[nt] = __builtin_amdgcn_mfma_f32_16x16x32_f16(H1, B1, g4[nt], 0,0,0);
  }
  if (mode != 2){
    #pragma unroll
    for (int r=0;r<4;r++){
      if (!ok_[r]) continue;
      const float* wr = embWf + (size_t)wt_[r]*HDIM;
      int j = j0 + q*4 + r;
      #pragma unroll
      for (int nt=0;nt<4;nt++){
        int col = nt*16 + c16;
        float v = sigf(g4[nt][r] + wr[col]) * cc[r][nt];
        f16x2 o; o.x = hh[r][nt]; o.y = (f16)v;
        HFout[(size_t)j*HDIM + col] = o;          // contiguous streaming write
      }
    }
  } else {
    float sH[4] = {0.f,0.f,0.f,0.f};
    float sF[4] = {0.f,0.f,0.f,0.f};
    #pragma unroll
    for (int r=0;r<4;r++){
      if (!ok_[r]) continue;
      const float* wr = embWf + (size_t)wt_[r]*HDIM;
      #pragma unroll
      for (int nt=0;nt<4;nt++){
        int col = nt*16 + c16;
        float v = sigf(g4[nt][r] + wr[col]) * cc[r][nt];
        sH[nt] += (float)hh[r][nt];
        sF[nt] += v;
      }
    }
    int sl = (blockIdx.x*4 + wv) & (NS-1);
    #pragma unroll
    for (int nt=0;nt<4;nt++){
      int col = nt*16 + c16;
      atomicAdd(&rootslice[sl*128 + col],      sF[nt]);
      atomicAdd(&rootslice[sl*128 + 64 + col], sH[nt]);
    }
  }
}

// ================= root cell (reduces slices inline) =================
__global__ void rootnode_kernel(
    const int* __restrict__ tok, const float* __restrict__ emb,
    const float* __restrict__ Wiou, const float* __restrict__ biou, const float* __restrict__ Uiou,
    const float* __restrict__ rootslice, float* __restrict__ out)
{
  __shared__ float hsh[64];
  int m = threadIdx.x;
  if (m >= HDIM) return;
  float fcs = 0.f, hs = 0.f;
  for (int s=0; s<NS; ++s){
    fcs += rootslice[s*128 + m];
    hs  += rootslice[s*128 + 64 + m];
  }
  hsh[m] = hs;
  __syncthreads();
  int t = tok[0];
  float ai=biou[m], ao=biou[HDIM+m], au=biou[2*HDIM+m];
  for (int e=0;e<EDIM;e++){
    float xe = emb[(size_t)t*EDIM+e];
    ai += Wiou[(size_t)m*EDIM+e]*xe;
    ao += Wiou[(size_t)(HDIM+m)*EDIM+e]*xe;
    au += Wiou[(size_t)(2*HDIM+m)*EDIM+e]*xe;
  }
  for (int k=0;k<HDIM;k++){
    float hv = hsh[k];
    ai += Uiou[(size_t)m*HDIM+k]*hv;
    ao += Uiou[(size_t)(HDIM+m)*HDIM+k]*hv;
    au += Uiou[(size_t)(2*HDIM+m)*HDIM+k]*hv;
  }
  float c = sigf(ai)*tanh_f(au) + fcs;
  out[m] = sigf(ao)*tanh_f(c);
}

// ================= launch =================
static inline char* alignup(char* p){
  uintptr_t u = (uintptr_t)p;
  u = (u + 255) & ~(uintptr_t)255;
  return (char*)u;
}

extern "C" void kernel_launch(void* const* d_in, const int* in_sizes, int n_in,
                              void* d_out, int out_size, void* d_ws, size_t ws_size,
                              hipStream_t stream)
{
  const int*   tok    = (const int*)d_in[0];
  const int*   parent = (const int*)d_in[1];
  const float* emb    = (const float*)d_in[4];
  const float* Wiou   = (const float*)d_in[5];
  const float* biou   = (const float*)d_in[6];
  const float* Uiou   = (const float*)d_in[7];
  const float* Wf     = (const float*)d_in[8];
  const float* bf     = (const float*)d_in[9];
  const float* Uf     = (const float*)d_in[10];
  float* out = (float*)d_out;

  char* w = (char*)d_ws;
  size_t BUF = (size_t)PER*HDIM*sizeof(f16x2);     // 38.3 MB
  f16x2* HFA       = (f16x2*)w;  w = alignup(w + BUF);
  f16x2* HFB       = (f16x2*)w;  w = alignup(w + BUF);
  int*   sposA     = (int*)w;    w = alignup(w + (size_t)PER*sizeof(int));
  int*   sposB     = (int*)w;    w = alignup(w + (size_t)PER*sizeof(int));
  int*   cnt       = (int*)w;    w = alignup(w + (size_t)PER*sizeof(int));
  int*   cursor    = (int*)w;    w = alignup(w + (size_t)PER*sizeof(int));
  int*   bsum      = (int*)w;    w = alignup(w + 256*sizeof(int));
  int*   soff_all  = (int*)w;    w = alignup(w + (size_t)6*(PER+1)*sizeof(int));
  int*   stok_all  = (int*)w;    w = alignup(w + (size_t)7*PER*sizeof(int));
  int*   ptok_all  = (int*)w;    w = alignup(w + (size_t)7*PER*sizeof(int));
  float* embWiou   = (float*)w;  w = alignup(w + 1024*NIOU*sizeof(float));
  float* embWf     = (float*)w;  w = alignup(w + 1024*HDIM*sizeof(float));
  float* rootslice = (float*)w;  w = alignup(w + (size_t)NS*128*sizeof(float));
  f16*   Ufpack    = (f16*)w;    w = alignup(w + 2*4*64*8*sizeof(f16));
  f16*   Biopack   = (f16*)w;    w = alignup(w + 2*12*64*8*sizeof(f16));

  const int gPER = (PER + 255)/256;   // 586
  const int gSCN = (PER + 1023)/1024; // 147
  const int NBL  = (PER + 63)/64;     // 2341

  (void)hipMemsetAsync(cnt, 0, (size_t)PER*sizeof(int), stream);
  (void)hipMemsetAsync(rootslice, 0, (size_t)NS*128*sizeof(float), stream);
  tablepack_kernel<<<1025, 256, 0, stream>>>(emb, Wiou, biou, Wf, bf, Uf, Uiou,
                                             embWiou, embWf, Ufpack, Biopack);
  init1_kernel<<<gPER, 256, 0, stream>>>(tok, sposA, stok_all, ptok_all, soff_all);

  // cascaded sort: level d's children (level d+1) sorted by parent's sorted pos
  int* spos_cur = sposA; int* spos_nxt = sposB;
  for (int d=1; d<=6; ++d){
    int poff = 1 + (d-1)*PER;
    int coff = 1 + d*PER;
    countL_kernel <<<gPER, 256, 0, stream>>>(parent, spos_cur, cnt, coff, poff);
    scan1_kernel  <<<gSCN, 256, 0, stream>>>(cnt, bsum);
    scan23_kernel <<<gSCN, 256, 0, stream>>>(cnt, bsum,
                                             soff_all + (size_t)(d-1)*(PER+1), cursor);
    scatterL_kernel<<<gPER, 256, 0, stream>>>(parent, tok, spos_cur, cursor, spos_nxt,
                                              stok_all + (size_t)d*PER,
                                              ptok_all + (size_t)d*PER,
                                              cnt, coff, poff);
    int* t2 = spos_cur; spos_cur = spos_nxt; spos_nxt = t2;
  }

  // d=7 leaves (mode 0) -> HFA; d=6..2 mids (mode 1) ping-pong; d=1 fused root (mode 2)
  level_kernel<<<NBL, 256, 0, stream>>>(stok_all + (size_t)6*PER, ptok_all + (size_t)6*PER,
                                        nullptr, embWiou, embWf, Biopack, Ufpack,
                                        nullptr, HFA, rootslice, 0);
  f16x2* in = HFA; f16x2* ob = HFB;
  for (int d=6; d>=2; --d){
    level_kernel<<<NBL, 256, 0, stream>>>(stok_all + (size_t)(d-1)*PER,
                                          ptok_all + (size_t)(d-1)*PER,
                                          soff_all + (size_t)(d-1)*(PER+1),
                                          embWiou, embWf, Biopack, Ufpack,
                                          in, ob, rootslice, 1);
    f16x2* t2 = in; in = ob; ob = t2;
  }
  level_kernel<<<NBL, 256, 0, stream>>>(stok_all, ptok_all, soff_all,
                                        embWiou, embWf, Biopack, Ufpack,
                                        in, ob /*unused*/, rootslice, 2);

  rootnode_kernel<<<1, 64, 0, stream>>>(tok, emb, Wiou, biou, Uiou, rootslice, out);
}